// Round 2
// baseline (397.834 us; speedup 1.0000x reference)
//
#include <hip/hip_runtime.h>

// MorphoMLP: y = relu(maxplus(relu(maxplus(x,W1)), W2)), fp32.
// B=512, IN=512, HID=1024, OUT=512.
// R4: atomicMax-combine restructure.
//   - relu(max_z p) == max_z relu(p); relu'd floats >=0 so fp32 order == uint
//     order -> zero the output and atomicMax(__float_as_uint(v)). Bit-exact,
//     order-independent. Deletes combineH/combineY and 64MB partial traffic.
//   - splitK now storage-free -> 1024 blocks/morpho (4 blk/CU, 4 waves/SIMD
//     with __launch_bounds__(256,4)) for latency hiding (R2/R3 had 2/SIMD).
//   - 128x128 tile, 8jx8b frags/thread (1.0 B/update delivery), Kchunk=16.
//   - frag split lo/hi (tx*4 and 64+tx*4): ds_read_b128 lane stride 16B ->
//     2-way bank alias (free) instead of 32B stride (4-way).
// ws: xT 1MB | W1T 2MB | W2T 2MB | A2 2MB = 7MB

#define WS_XT   0                          // [512][512]    x^T  [k][b]
#define WS_W1T  (512 * 512)                // [512][1024]   W1^T [k][j]
#define WS_W2T  (WS_W1T + 512 * 1024)      // [1024][512]   W2^T [k2][o]
#define WS_A2   (WS_W2T + 1024 * 512)      // [1024][512]   relu(h)^T [k2][b]

typedef float f32x2 __attribute__((ext_vector_type(2)));

// ---------------------------------------------------------------------------
// Fused transpose of x (512x512), W1 (1024x512), W2 (512x1024) into ws.
__global__ __launch_bounds__(256) void transpose3(const float* __restrict__ x,
                                                  const float* __restrict__ W1,
                                                  const float* __restrict__ W2,
                                                  float* __restrict__ ws) {
    __shared__ float t[32][33];
    const int id = blockIdx.x;
    const float* src;
    float* dst;
    int R, C, rt, ct;
    if (id < 256) {
        src = x;  dst = ws + WS_XT;  R = 512;  C = 512;
        rt = id >> 4;          ct = id & 15;
    } else if (id < 768) {
        int b = id - 256;
        src = W1; dst = ws + WS_W1T; R = 1024; C = 512;
        rt = b >> 4;           ct = b & 15;
    } else {
        int b = id - 768;
        src = W2; dst = ws + WS_W2T; R = 512;  C = 1024;
        rt = b >> 5;           ct = b & 31;
    }
    const int tx = threadIdx.x & 31, ty = threadIdx.x >> 5;
    const int r0 = rt * 32, c0 = ct * 32;
#pragma unroll
    for (int r = 0; r < 4; r++)
        t[ty + 8 * r][tx] = src[(size_t)(r0 + ty + 8 * r) * C + c0 + tx];
    __syncthreads();
#pragma unroll
    for (int r = 0; r < 4; r++)
        dst[(size_t)(c0 + ty + 8 * r) * R + r0 + tx] = t[tx][ty + 8 * r];
}

// ---------------------------------------------------------------------------
// Zero A2 (2MB = 131072 float4) and d_out (1MB = 65536 float4).
__global__ __launch_bounds__(256) void zeroAY(float* __restrict__ a2,
                                              float* __restrict__ out) {
    const int i = blockIdx.x * 256 + threadIdx.x;
    const float4 z = make_float4(0.f, 0.f, 0.f, 0.f);
    if (i < 131072) ((float4*)a2)[i] = z;
    else            ((float4*)out)[i - 131072] = z;
}

// ---------------------------------------------------------------------------
// Max-plus tile kernel with fused relu + atomicMax combine.
// A: [K][512] K-major activations; W: [K][JDIM] K-major weights.
// Block tile: 128 j x 128 b x 16 k. 256 threads, 8j x 8b frags/thread.
// Frags are split lo/hi: j = {ty*4..+3} u {64+ty*4..+3}, b likewise with tx.
// acc starts at 0 (== relu clamp folded in); result written with
// atomicMax(uint) — exact for non-negative IEEE floats.
// BMAJOR=0: Out[j*512 + b] (A2 layout);  BMAJOR=1: Out[b*512 + j] (final y).
template <int JDIM, int BMAJOR>
__global__ __launch_bounds__(256, 4) void morpho4(const float* __restrict__ A,
                                                  const float* __restrict__ W,
                                                  unsigned int* __restrict__ Out) {
    __shared__ float lA[16 * 128];   // [k][b] 8KB
    __shared__ float lW[16 * 128];   // [k][j] 8KB
    const int t  = threadIdx.x;
    const int tx = t & 15;           // b frag base
    const int ty = t >> 4;           // j frag base
    const int j0 = blockIdx.x * 128;
    const int b0 = blockIdx.y * 128;
    const int k0 = blockIdx.z * 16;

    // ---- stage both tiles: 512 float4 each, 2/thread ----
    {
        const int q0 = t, q1 = t + 256;          // row = q>>5, col f4 = q&31
        ((float4*)lA)[q0] = *((const float4*)(A + (size_t)(k0 + (q0 >> 5)) * 512 + b0) + (q0 & 31));
        ((float4*)lA)[q1] = *((const float4*)(A + (size_t)(k0 + (q1 >> 5)) * 512 + b0) + (q1 & 31));
        ((float4*)lW)[q0] = *((const float4*)(W + (size_t)(k0 + (q0 >> 5)) * JDIM + j0) + (q0 & 31));
        ((float4*)lW)[q1] = *((const float4*)(W + (size_t)(k0 + (q1 >> 5)) * JDIM + j0) + (q1 & 31));
    }
    __syncthreads();

    float acc[8][8];                 // [jrow][bcol], init 0 == relu fold
#pragma unroll
    for (int jj = 0; jj < 8; jj++)
#pragma unroll
        for (int i = 0; i < 8; i++) acc[jj][i] = 0.0f;

    const float4* lA4 = (const float4*)lA;
    const float4* lW4 = (const float4*)lW;

    // ---- inner max-plus: 2 k's per iter; pk-adds + v_max3 merge ----
#pragma unroll
    for (int kk = 0; kk < 16; kk += 2) {
        const float4 aL0 = lA4[kk * 32 + tx];        // k, b lo
        const float4 aH0 = lA4[kk * 32 + 16 + tx];   // k, b hi
        const float4 aL1 = lA4[kk * 32 + 32 + tx];   // k+1, b lo
        const float4 aH1 = lA4[kk * 32 + 48 + tx];   // k+1, b hi
        const float4 wL0 = lW4[kk * 32 + ty];        // k, j lo
        const float4 wH0 = lW4[kk * 32 + 16 + ty];   // k, j hi
        const float4 wL1 = lW4[kk * 32 + 32 + ty];   // k+1, j lo
        const float4 wH1 = lW4[kk * 32 + 48 + ty];   // k+1, j hi

        const f32x2 aL0p0 = {aL0.x, aL0.y}, aL0p1 = {aL0.z, aL0.w};
        const f32x2 aH0p0 = {aH0.x, aH0.y}, aH0p1 = {aH0.z, aH0.w};
        const f32x2 aL1p0 = {aL1.x, aL1.y}, aL1p1 = {aL1.z, aL1.w};
        const f32x2 aH1p0 = {aH1.x, aH1.y}, aH1p1 = {aH1.z, aH1.w};

#define UPDJ(JR, W0, W1)                                                    \
    {                                                                       \
        const f32x2 wa = {(W0), (W0)};                                      \
        const f32x2 wb = {(W1), (W1)};                                      \
        const f32x2 s0 = aL0p0 + wa, t0 = aL1p0 + wb;                       \
        const f32x2 s1 = aL0p1 + wa, t1 = aL1p1 + wb;                       \
        const f32x2 s2 = aH0p0 + wa, t2 = aH1p0 + wb;                       \
        const f32x2 s3 = aH0p1 + wa, t3 = aH1p1 + wb;                       \
        acc[JR][0] = fmaxf(fmaxf(acc[JR][0], s0.x), t0.x);                  \
        acc[JR][1] = fmaxf(fmaxf(acc[JR][1], s0.y), t0.y);                  \
        acc[JR][2] = fmaxf(fmaxf(acc[JR][2], s1.x), t1.x);                  \
        acc[JR][3] = fmaxf(fmaxf(acc[JR][3], s1.y), t1.y);                  \
        acc[JR][4] = fmaxf(fmaxf(acc[JR][4], s2.x), t2.x);                  \
        acc[JR][5] = fmaxf(fmaxf(acc[JR][5], s2.y), t2.y);                  \
        acc[JR][6] = fmaxf(fmaxf(acc[JR][6], s3.x), t3.x);                  \
        acc[JR][7] = fmaxf(fmaxf(acc[JR][7], s3.y), t3.y);                  \
    }
        UPDJ(0, wL0.x, wL1.x)
        UPDJ(1, wL0.y, wL1.y)
        UPDJ(2, wL0.z, wL1.z)
        UPDJ(3, wL0.w, wL1.w)
        UPDJ(4, wH0.x, wH1.x)
        UPDJ(5, wH0.y, wH1.y)
        UPDJ(6, wH0.z, wH1.z)
        UPDJ(7, wH0.w, wH1.w)
#undef UPDJ
    }

    // ---- fused combine: atomicMax (values >= 0, uint order == fp order) ----
#pragma unroll
    for (int jj = 0; jj < 8; jj++) {
        const int jl = ((jj >> 2) << 6) + ty * 4 + (jj & 3);
#pragma unroll
        for (int bi = 0; bi < 8; bi++) {
            const int bl = ((bi >> 2) << 6) + tx * 4 + (bi & 3);
            const unsigned int v = __float_as_uint(acc[jj][bi]);
            const size_t idx = BMAJOR ? ((size_t)(b0 + bl) * 512 + (j0 + jl))
                                      : ((size_t)(j0 + jl) * 512 + (b0 + bl));
            atomicMax(Out + idx, v);
        }
    }
}

// ---------------------------------------------------------------------------
extern "C" void kernel_launch(void* const* d_in, const int* in_sizes, int n_in,
                              void* d_out, int out_size, void* d_ws, size_t ws_size,
                              hipStream_t stream) {
    (void)in_sizes; (void)n_in; (void)out_size; (void)ws_size;
    const float* x  = (const float*)d_in[0];
    const float* W1 = (const float*)d_in[1];
    const float* W2 = (const float*)d_in[2];
    float* ws  = (float*)d_ws;
    float* out = (float*)d_out;

    // 1) K-major transposes of x, W1, W2
    transpose3<<<1280, 256, 0, stream>>>(x, W1, W2, ws);

    // 2) zero the atomicMax targets (A2 + out)
    zeroAY<<<768, 256, 0, stream>>>(ws + WS_A2, out);

    // 3) L1: A2[j][b] = relu(max_k x^T + W1^T); grid 8(j) x 4(b) x 32(kz)
    morpho4<1024, 0><<<dim3(8, 4, 32), 256, 0, stream>>>(
        ws + WS_XT, ws + WS_W1T, (unsigned int*)(ws + WS_A2));

    // 4) L2: out[b][o] = relu(max_k2 A2 + W2^T); grid 4(o) x 4(b) x 64(kz)
    morpho4<512, 1><<<dim3(4, 4, 64), 256, 0, stream>>>(
        ws + WS_A2, ws + WS_W2T, (unsigned int*)out);
}

// Round 3
// 97.362 us; speedup vs baseline: 4.0861x; 4.0861x over previous
//
#include <hip/hip_runtime.h>

// MorphoMLP: y = relu(maxplus(relu(maxplus(x,W1)), W2)), fp32.
// B=512, IN=512, HID=1024, OUT=512.
// R5: back to the R2 split-K + combine structure (atomics were 268MB of HBM
//     writes + serialization; partials are L3-resident and cheap), but fix
//     the occupancy that capped R2/R3:
//   - 64j x 64b x 64k tiles, 4x4 frag/thread -> 1024 blocks per morpho
//     (4 blocks/CU, 4 waves/SIMD; R2 had 2) with 32KB LDS/block.
//   - pk_add f32x2 + v_max3 inner loop: 1.0 VALU instr/update (R2: 1.5).
//   - combineH/combineY + ws layout identical to the 97µs R2 baseline.
// ws: xT 1MB | W1T 2MB | W2T 2MB | hp 16MB | A2 2MB | yp 16MB  = 39MB

#define WS_XT   0                          // [512][512]    x^T  [k][b]
#define WS_W1T  (512 * 512)                // [512][1024]   W1^T [k][j]
#define WS_W2T  (WS_W1T + 512 * 1024)      // [1024][512]   W2^T [k2][o]
#define WS_HP   (WS_W2T + 1024 * 512)      // [8][1024][512]  L1 partials
#define WS_A2   (WS_HP + 8 * 1024 * 512)   // [1024][512]   relu(h)^T [k2][b]
#define WS_YP   (WS_A2 + 1024 * 512)       // [16][512][512]  L2 partials

typedef float f32x2 __attribute__((ext_vector_type(2)));

// ---------------------------------------------------------------------------
// Fused transpose of x (512x512), W1 (1024x512), W2 (512x1024) into ws.
__global__ __launch_bounds__(256) void transpose3(const float* __restrict__ x,
                                                  const float* __restrict__ W1,
                                                  const float* __restrict__ W2,
                                                  float* __restrict__ ws) {
    __shared__ float t[32][33];
    const int id = blockIdx.x;
    const float* src;
    float* dst;
    int R, C, rt, ct;
    if (id < 256) {
        src = x;  dst = ws + WS_XT;  R = 512;  C = 512;
        rt = id >> 4;          ct = id & 15;
    } else if (id < 768) {
        int b = id - 256;
        src = W1; dst = ws + WS_W1T; R = 1024; C = 512;
        rt = b >> 4;           ct = b & 15;
    } else {
        int b = id - 768;
        src = W2; dst = ws + WS_W2T; R = 512;  C = 1024;
        rt = b >> 5;           ct = b & 31;
    }
    const int tx = threadIdx.x & 31, ty = threadIdx.x >> 5;
    const int r0 = rt * 32, c0 = ct * 32;
#pragma unroll
    for (int r = 0; r < 4; r++)
        t[ty + 8 * r][tx] = src[(size_t)(r0 + ty + 8 * r) * C + c0 + tx];
    __syncthreads();
#pragma unroll
    for (int r = 0; r < 4; r++)
        dst[(size_t)(c0 + ty + 8 * r) * R + r0 + tx] = t[tx][ty + 8 * r];
}

// ---------------------------------------------------------------------------
// Max-plus tile kernel. A: [K][512] K-major activations; W: [K][JDIM] K-major.
// Block tile: 64 j x 64 b x 64 k. 256 threads, 4j x 4b frag/thread.
// acc init 0 folds the downstream relu (relu(max(0,p)) == relu(p)).
// Stores raw partial transposed: P[z][j][b].
template <int JDIM>
__global__ __launch_bounds__(256, 4) void morpho6(const float* __restrict__ A,
                                                  const float* __restrict__ W,
                                                  float* __restrict__ P) {
    __shared__ float lA[64 * 64];    // [k][b] 16KB
    __shared__ float lW[64 * 64];    // [k][j] 16KB
    const int t  = threadIdx.x;
    const int tx = t & 15;           // b frag: b0 + tx*4 + {0..3}
    const int ty = t >> 4;           // j frag: j0 + ty*4 + {0..3}
    const int j0 = blockIdx.x * 64;
    const int b0 = blockIdx.y * 64;
    const int k0 = blockIdx.z * 64;

    // ---- stage tiles: 1024 float4 each, 4/thread, fully coalesced ----
    const float4* A4 = (const float4*)(A + (size_t)k0 * 512) + (b0 >> 2);
    const float4* W4 = (const float4*)(W + (size_t)k0 * JDIM) + (j0 >> 2);
#pragma unroll
    for (int r = 0; r < 4; r++) {
        const int q   = t + 256 * r;
        const int row = q >> 4, col = q & 15;     // 16 f4 per 64-float row
        ((float4*)lA)[q] = A4[(size_t)row * 128 + col];
        ((float4*)lW)[q] = W4[(size_t)row * (JDIM / 4) + col];
    }
    __syncthreads();

    float acc[4][4];                 // [j][b], init 0 == relu fold
#pragma unroll
    for (int jj = 0; jj < 4; jj++)
#pragma unroll
        for (int i = 0; i < 4; i++) acc[jj][i] = 0.0f;

    const float4* lA4 = (const float4*)lA;
    const float4* lW4 = (const float4*)lW;

    // ---- inner max-plus: 2 k's/iter; pk adds (f32x2) + v_max3 merges ----
#pragma unroll 8
    for (int kk = 0; kk < 64; kk += 2) {
        const float4 a0 = lA4[kk * 16 + tx];         // k,   b frag
        const float4 a1 = lA4[kk * 16 + 16 + tx];    // k+1, b frag
        const float4 w0 = lW4[kk * 16 + ty];         // k,   j frag
        const float4 w1 = lW4[kk * 16 + 16 + ty];    // k+1, j frag

        const f32x2 a0p0 = {a0.x, a0.y}, a0p1 = {a0.z, a0.w};
        const f32x2 a1p0 = {a1.x, a1.y}, a1p1 = {a1.z, a1.w};

#define UPDJ(JR, W0, W1)                                                    \
    {                                                                       \
        const f32x2 wa = {(W0), (W0)};                                      \
        const f32x2 wb = {(W1), (W1)};                                      \
        const f32x2 s0 = a0p0 + wa, t0 = a1p0 + wb;                         \
        const f32x2 s1 = a0p1 + wa, t1 = a1p1 + wb;                         \
        acc[JR][0] = fmaxf(fmaxf(acc[JR][0], s0.x), t0.x);                  \
        acc[JR][1] = fmaxf(fmaxf(acc[JR][1], s0.y), t0.y);                  \
        acc[JR][2] = fmaxf(fmaxf(acc[JR][2], s1.x), t1.x);                  \
        acc[JR][3] = fmaxf(fmaxf(acc[JR][3], s1.y), t1.y);                  \
    }
        UPDJ(0, w0.x, w1.x)
        UPDJ(1, w0.y, w1.y)
        UPDJ(2, w0.z, w1.z)
        UPDJ(3, w0.w, w1.w)
#undef UPDJ
    }

    // ---- store transposed partial: P[z][j][b], float4 over b (coalesced) ----
    float* Pp = P + (size_t)blockIdx.z * JDIM * 512;
#pragma unroll
    for (int jj = 0; jj < 4; jj++) {
        const float4 v = make_float4(acc[jj][0], acc[jj][1], acc[jj][2], acc[jj][3]);
        *(float4*)(Pp + (size_t)(j0 + ty * 4 + jj) * 512 + b0 + tx * 4) = v;
    }
}

// ---------------------------------------------------------------------------
// combineH: A2[j][b] = relu(max_z hp[z][j][b]).  Already K-major for L2.
// 512 blocks x 256 thr x 1 float4 = 512K floats.
__global__ __launch_bounds__(256) void combineH(const float* __restrict__ hp,
                                                float* __restrict__ A2) {
    const int i = blockIdx.x * 256 + threadIdx.x;   // float4 index
    const float4* p = (const float4*)hp;
    float4 m = p[i];
#pragma unroll
    for (int z = 1; z < 8; z++) {
        const float4 v = p[i + z * 131072];         // 512K floats / 4
        m.x = fmaxf(m.x, v.x);
        m.y = fmaxf(m.y, v.y);
        m.z = fmaxf(m.z, v.z);
        m.w = fmaxf(m.w, v.w);
    }
    m.x = fmaxf(m.x, 0.0f);
    m.y = fmaxf(m.y, 0.0f);
    m.z = fmaxf(m.z, 0.0f);
    m.w = fmaxf(m.w, 0.0f);
    ((float4*)A2)[i] = m;
}

// ---------------------------------------------------------------------------
// combineY: out[b][o] = relu(max_z yp[z][o][b]); 16 partials + transpose.
__global__ __launch_bounds__(256) void combineY(const float* __restrict__ yp,
                                                float* __restrict__ out) {
    __shared__ float t[32][33];
    const int id = blockIdx.x;
    const int ot = id & 15, bt = id >> 4;
    const int tx = threadIdx.x & 31, ty = threadIdx.x >> 5;
    const int o0 = ot * 32, b0 = bt * 32;
#pragma unroll
    for (int r = 0; r < 4; r++) {
        const int o   = o0 + ty + 8 * r;
        const int idx = o * 512 + b0 + tx;
        float m = yp[idx];
#pragma unroll
        for (int z = 1; z < 16; z++) m = fmaxf(m, yp[idx + z * 262144]);
        t[ty + 8 * r][tx] = fmaxf(m, 0.0f);
    }
    __syncthreads();
#pragma unroll
    for (int r = 0; r < 4; r++)
        out[(b0 + ty + 8 * r) * 512 + o0 + tx] = t[tx][ty + 8 * r];
}

// ---------------------------------------------------------------------------
extern "C" void kernel_launch(void* const* d_in, const int* in_sizes, int n_in,
                              void* d_out, int out_size, void* d_ws, size_t ws_size,
                              hipStream_t stream) {
    (void)in_sizes; (void)n_in; (void)out_size; (void)ws_size;
    const float* x  = (const float*)d_in[0];
    const float* W1 = (const float*)d_in[1];
    const float* W2 = (const float*)d_in[2];
    float* ws  = (float*)d_ws;
    float* out = (float*)d_out;

    // 1) K-major transposes of x, W1, W2
    transpose3<<<1280, 256, 0, stream>>>(x, W1, W2, ws);

    // 2) L1: hp[8][1024][512]; grid 16(j) x 8(b) x 8(kz), Kchunk=64, 1024 blk
    morpho6<1024><<<dim3(16, 8, 8), 256, 0, stream>>>(
        ws + WS_XT, ws + WS_W1T, ws + WS_HP);

    // 3) combine 8 partials + relu -> A2[k2][b]
    combineH<<<512, 256, 0, stream>>>(ws + WS_HP, ws + WS_A2);

    // 4) L2: yp[16][512][512]; grid 8(o) x 8(b) x 16(kz), Kchunk=64, 1024 blk
    morpho6<512><<<dim3(8, 8, 16), 256, 0, stream>>>(
        ws + WS_A2, ws + WS_W2T, ws + WS_YP);

    // 5) combine 16 partials + relu + transpose -> d_out[b][o]
    combineY<<<256, 256, 0, stream>>>(ws + WS_YP, out);
}

// Round 4
// 94.858 us; speedup vs baseline: 4.1940x; 1.0264x over previous
//
#include <hip/hip_runtime.h>

// MorphoMLP: y = relu(maxplus(relu(maxplus(x,W1)), W2)), fp32.
// B=512, IN=512, HID=1024, OUT=512.
// R6: 5 -> 4 kernels (R4 data: ~7.5us overhead per kernel boundary).
//   - combineH deleted: M2 folds the 4-slice max+relu into W-tile staging.
//   - L2 uses role-swap (W-role=h, A-role=W2T) so partials are yp[z][b][o];
//     combineY is a plain coalesced 8-way f4 max, no transpose.
//   - morpho inner loop bit-identical to R5 (pk_add f32x2 + v_max3).
//   - M1: 64x64 tile, z=4 (KPER=128) -> 512 blocks; M2: z=8 -> 512 blocks.
// ws: xT 1MB | W1T 2MB | W2T 2MB | hp 8MB | yp 8MB = 21MB

#define WS_XT   0                           // [512][512]    x^T  [k][b]
#define WS_W1T  (512 * 512)                 // [512][1024]   W1^T [k][j]
#define WS_W2T  (WS_W1T + 512 * 1024)       // [1024][512]   W2^T [k2][o]
#define WS_HP   (WS_W2T + 1024 * 512)       // [4][1024][512]  L1 partials
#define WS_YP   (WS_HP + 4 * 1024 * 512)    // [8][512][512]   L2 partials [z][b][o]

typedef float f32x2 __attribute__((ext_vector_type(2)));

__device__ __forceinline__ float4 fmax4(float4 a, float4 b) {
    return make_float4(fmaxf(a.x, b.x), fmaxf(a.y, b.y),
                       fmaxf(a.z, b.z), fmaxf(a.w, b.w));
}

// ---------------------------------------------------------------------------
// Fused transpose of x (512x512), W1 (1024x512), W2 (512x1024) into ws.
__global__ __launch_bounds__(256) void transpose3(const float* __restrict__ x,
                                                  const float* __restrict__ W1,
                                                  const float* __restrict__ W2,
                                                  float* __restrict__ ws) {
    __shared__ float t[32][33];
    const int id = blockIdx.x;
    const float* src;
    float* dst;
    int R, C, rt, ct;
    if (id < 256) {
        src = x;  dst = ws + WS_XT;  R = 512;  C = 512;
        rt = id >> 4;          ct = id & 15;
    } else if (id < 768) {
        int b = id - 256;
        src = W1; dst = ws + WS_W1T; R = 1024; C = 512;
        rt = b >> 4;           ct = b & 15;
    } else {
        int b = id - 768;
        src = W2; dst = ws + WS_W2T; R = 512;  C = 1024;
        rt = b >> 5;           ct = b & 31;
    }
    const int tx = threadIdx.x & 31, ty = threadIdx.x >> 5;
    const int r0 = rt * 32, c0 = ct * 32;
#pragma unroll
    for (int r = 0; r < 4; r++)
        t[ty + 8 * r][tx] = src[(size_t)(r0 + ty + 8 * r) * C + c0 + tx];
    __syncthreads();
#pragma unroll
    for (int r = 0; r < 4; r++)
        dst[(size_t)(c0 + ty + 8 * r) * R + r0 + tx] = t[tx][ty + 8 * r];
}

// ---------------------------------------------------------------------------
// Max-plus tile kernel. A-role: [K][512] K-major; W-role: [K][JDIM] K-major.
// Block tile: 64 j x 64 b x KPER k (staged in chunks of 64). 256 threads,
// 4j x 4b frag/thread. acc init 0 folds the downstream relu.
// ZFOLD>1: W-role staging reads ZFOLD slices (stride WSLICE f4) and takes
// elementwise max + relu — this fuses the previous layer's combine.
// Stores raw partial transposed: P[z][j][b] (f4 over b, coalesced).
template <int JDIM, int KPER, int ZFOLD, int WSLICE>
__global__ __launch_bounds__(256, 2) void morpho7(const float* __restrict__ A,
                                                  const float* __restrict__ W,
                                                  float* __restrict__ P) {
    __shared__ float lA[64 * 64];    // [k][b] 16KB
    __shared__ float lW[64 * 64];    // [k][j] 16KB
    const int t  = threadIdx.x;
    const int tx = t & 15;           // b frag: b0 + tx*4 + {0..3}
    const int ty = t >> 4;           // j frag: j0 + ty*4 + {0..3}
    const int j0 = blockIdx.x * 64;
    const int b0 = blockIdx.y * 64;
    const int k0 = blockIdx.z * KPER;

    float acc[4][4];                 // [j][b], init 0 == relu fold
#pragma unroll
    for (int jj = 0; jj < 4; jj++)
#pragma unroll
        for (int i = 0; i < 4; i++) acc[jj][i] = 0.0f;

    const float4* lA4 = (const float4*)lA;
    const float4* lW4 = (const float4*)lW;

    for (int ks = 0; ks < KPER; ks += 64) {
        if (ks) __syncthreads();     // WAR: all waves done reading prev tiles

        // ---- stage tiles: 1024 float4 each, 4/thread, coalesced ----
        const float4* A4 = (const float4*)(A + (size_t)(k0 + ks) * 512) + (b0 >> 2);
        const float4* W4 = (const float4*)(W + (size_t)(k0 + ks) * JDIM) + (j0 >> 2);
#pragma unroll
        for (int r = 0; r < 4; r++) {
            const int q   = t + 256 * r;
            const int row = q >> 4, col = q & 15;   // 16 f4 per 64-float row
            ((float4*)lA)[q] = A4[(size_t)row * 128 + col];
            const size_t woff = (size_t)row * (JDIM / 4) + col;
            float4 w = W4[woff];
            if (ZFOLD > 1) {
#pragma unroll
                for (int z = 1; z < ZFOLD; z++)
                    w = fmax4(w, W4[woff + (size_t)z * WSLICE]);
                w = fmax4(w, make_float4(0.f, 0.f, 0.f, 0.f));   // relu
            }
            ((float4*)lW)[q] = w;
        }
        __syncthreads();

        // ---- inner max-plus: 2 k's/iter; pk adds (f32x2) + v_max3 merges ----
#pragma unroll 8
        for (int kk = 0; kk < 64; kk += 2) {
            const float4 a0 = lA4[kk * 16 + tx];         // k,   b frag
            const float4 a1 = lA4[kk * 16 + 16 + tx];    // k+1, b frag
            const float4 w0 = lW4[kk * 16 + ty];         // k,   j frag
            const float4 w1 = lW4[kk * 16 + 16 + ty];    // k+1, j frag

            const f32x2 a0p0 = {a0.x, a0.y}, a0p1 = {a0.z, a0.w};
            const f32x2 a1p0 = {a1.x, a1.y}, a1p1 = {a1.z, a1.w};

#define UPDJ(JR, W0, W1)                                                    \
    {                                                                       \
        const f32x2 wa = {(W0), (W0)};                                      \
        const f32x2 wb = {(W1), (W1)};                                      \
        const f32x2 s0 = a0p0 + wa, t0 = a1p0 + wb;                         \
        const f32x2 s1 = a0p1 + wa, t1 = a1p1 + wb;                         \
        acc[JR][0] = fmaxf(fmaxf(acc[JR][0], s0.x), t0.x);                  \
        acc[JR][1] = fmaxf(fmaxf(acc[JR][1], s0.y), t0.y);                  \
        acc[JR][2] = fmaxf(fmaxf(acc[JR][2], s1.x), t1.x);                  \
        acc[JR][3] = fmaxf(fmaxf(acc[JR][3], s1.y), t1.y);                  \
    }
            UPDJ(0, w0.x, w1.x)
            UPDJ(1, w0.y, w1.y)
            UPDJ(2, w0.z, w1.z)
            UPDJ(3, w0.w, w1.w)
#undef UPDJ
        }
    }

    // ---- store transposed partial: P[z][j][b], float4 over b (coalesced) ----
    float* Pp = P + (size_t)blockIdx.z * JDIM * 512;
#pragma unroll
    for (int jj = 0; jj < 4; jj++) {
        const float4 v = make_float4(acc[jj][0], acc[jj][1], acc[jj][2], acc[jj][3]);
        *(float4*)(Pp + (size_t)(j0 + ty * 4 + jj) * 512 + b0 + tx * 4) = v;
    }
}

// ---------------------------------------------------------------------------
// combineY: out[b][o] = max_z yp[z][b][o] — partials already relu-clamped
// (acc init 0) and already in [b][o] layout. Pure coalesced f4 max.
// 256 blocks x 256 thr x 1 float4 = 256K floats.
__global__ __launch_bounds__(256) void combineY2(const float* __restrict__ yp,
                                                 float* __restrict__ out) {
    const int i = blockIdx.x * 256 + threadIdx.x;   // float4 index
    const float4* p = (const float4*)yp;
    float4 m = p[i];
#pragma unroll
    for (int z = 1; z < 8; z++) m = fmax4(m, p[i + z * 65536]);  // 256K floats/4
    ((float4*)out)[i] = m;
}

// ---------------------------------------------------------------------------
extern "C" void kernel_launch(void* const* d_in, const int* in_sizes, int n_in,
                              void* d_out, int out_size, void* d_ws, size_t ws_size,
                              hipStream_t stream) {
    (void)in_sizes; (void)n_in; (void)out_size; (void)ws_size;
    const float* x  = (const float*)d_in[0];
    const float* W1 = (const float*)d_in[1];
    const float* W2 = (const float*)d_in[2];
    float* ws  = (float*)d_ws;
    float* out = (float*)d_out;

    // 1) K-major transposes of x, W1, W2
    transpose3<<<1280, 256, 0, stream>>>(x, W1, W2, ws);

    // 2) L1: hp[4][1024][512]; grid 16(j) x 8(b) x 4(z), KPER=128
    morpho7<1024, 128, 1, 1><<<dim3(16, 8, 4), 256, 0, stream>>>(
        ws + WS_XT, ws + WS_W1T, ws + WS_HP);

    // 3) L2 role-swapped: j-axis = batch b, b-axis = o. W-role = h (folded
    //    from 4 hp slices + relu during staging), A-role = W2T.
    //    yp[8][512(b)][512(o)]; grid 8(b) x 8(o) x 8(z), KPER=128.
    //    hp slice stride = 1024*512/4 = 131072 f4.
    morpho7<512, 128, 4, 131072><<<dim3(8, 8, 8), 256, 0, stream>>>(
        ws + WS_W2T, ws + WS_HP, ws + WS_YP);

    // 4) combine 8 partials -> d_out[b][o] (no transpose, values pre-relu'd)
    combineY2<<<256, 256, 0, stream>>>(ws + WS_YP, out);
}